// Round 9
// baseline (80.717 us; speedup 1.0000x reference)
//
#include <hip/hip_runtime.h>
#include <stdint.h>

// Problem constants (fixed by setup_inputs)
#define BB 64
#define TT 8192
// max_phrase_len = 32, pad_token_id = 0 (hardcoded)

#define NB   1024                      // blocks (4/CU -> whole grid co-resident)
#define TPB  512                       // threads per block
#define BPR  16                        // blocks per row

// Workspace layout (byte offsets)
#define WS_CNT    0                    // int[BB] row completion counters (memset each call)
#define WS_PAIR   4096                 // ulonglong2[BB*128]  {nat, real} per 64-token word

#define MOFF ((long long)BB * TT * 32) // ints in mask (= ints in tok)

__device__ __forceinline__ unsigned long long bitsBelow(int e) {  // bits 0..e-1, e in [0,64]
    return (e >= 64) ? ~0ULL : ((1ULL << e) - 1ULL);
}

__device__ __forceinline__ bool lut(const void* tbl, int flag, int idx) {
    if (flag == 2) return ((const float*)tbl)[idx]   != 0.0f;
    if (flag == 1) return ((const uint8_t*)tbl)[idx] != 0;
    return ((const int*)tbl)[idx] != 0;
}

// ---------------------------------------------------------------------------
// mono_kernel: whole pipeline, ONE dispatch.  1024 blocks x 512 threads.
//  1) dtype probe of bool tables (0=int32,1=uint8,2=float32) on 4KB.
//  2) background fill of this block's 1/1024 share of the output:
//     mask=0, tok=0 (16 int4/thread), end=-1 (1 int/thread) -- correct for
//     ~95% of phrase slots since nf << 8192.  Pure streaming stores.
//  3) natural/real bits for this block's 512 tokens (verified r6/r8 code):
//       natural[t] = real && ((punct[id] && !(t>0 && abbr[prev])) || t==last_real)
//       t==last_real local (real prefix): real[t] && (t==T-1 || !real[t+1])
//     ballot-packed {nat,real} -> pairW.
//  4) fence-counter: tid0 does ACQ_REL AGENT-scope fetch_add on rowCnt[row]
//     (release publishes this block's zeros+bits across XCDs; acquire on the
//     last block invalidates before reading other blocks' pairW words).
//     The block seeing old==BPR-1 becomes the row's scanner:
//  5) wave 0: verified word-parallel fire scan:
//       fire[t] = real[t] && (natural[t] || t === prevNat(t) (mod 32))
//     (init -1 => forced at t%32==31); prevNat carries = exclusive MAX-scan
//     of per-word last-natural positions; per-word fire bits via segment
//     walk; compaction via exclusive ADD-scan.  Fire list -> LDS.
//  6) all 512 threads sparse-rewrite phrases p < nf of this row.
//     Output determinism: whichever block is last does identical work.
// ---------------------------------------------------------------------------
__global__ __launch_bounds__(TPB) void mono_kernel(
        const int* __restrict__ ids,
        const void* __restrict__ punct,
        const void* __restrict__ abbr,
        ulonglong2* __restrict__ pairW,
        int* __restrict__ rowCnt,
        int* __restrict__ out) {
    __shared__ int sFires[TT];
    __shared__ int sFlag, sLast, sNf;

    int tid = threadIdx.x;
    if (tid == 0) sFlag = 0;
    __syncthreads();
    {   // probe first 1024 int32 words (4KB; in-bounds for all 3 layouts)
        const uint32_t* w = (const uint32_t*)punct;
        bool byteGT1 = false, wordGT1 = false;
#pragma unroll
        for (int j = 0; j < 2; ++j) {
            uint32_t x = w[tid * 2 + j];
            byteGT1 |= (x & 0xFEFEFEFEu) != 0u;   // f32: 1.0f has high bytes set
            wordGT1 |= (x > 1u);                  // uint8: packed bools > 1
        }
        int local = (byteGT1 ? 2 : 0) | (wordGT1 ? 1 : 0);
        if (local) atomicOr(&sFlag, local);
    }
    __syncthreads();
    int fl = sFlag;
    int flag = (fl & 2) ? 2 : (fl & 1);

    // 2) background fill: 32768 ints (mask+tok) + 512 ints (end) per block
    {
        long long zbase = (long long)blockIdx.x * 32768;
        int4 z = make_int4(0, 0, 0, 0);
#pragma unroll
        for (int k = 0; k < 16; ++k) {
            *(int4*)(out + zbase + k * 2048 + tid * 4) = z;
        }
        out[2 * MOFF + blockIdx.x * TPB + tid] = -1;
    }

    // 3) natural/real bits for this block's 512 tokens
    int g = blockIdx.x * TPB + tid;           // g = b*TT + t
    int t = g & (TT - 1);
    int b = g >> 13;
    {
        int id = ids[g];
        bool real = (id != 0);
        bool isLR = real && ((t == TT - 1) || (ids[g + 1] == 0));
        bool e = false;
        if (real) {
            bool pu = lut(punct, flag, id);
            if (pu) {                          // abbr gather predicated (~5%)
                bool pa = (t > 0) ? lut(abbr, flag, ids[g - 1]) : false;
                e = !pa;
            }
        }
        bool natural = real && (e || isLR);
        unsigned long long nb = __ballot(natural);
        unsigned long long rb = __ballot(real);
        if ((tid & 63) == 0) {
            pairW[g >> 6] = make_ulonglong2(nb, rb);   // word = b*128 + (t>>6)
        }
    }
    __syncthreads();   // drain block's stores (vmcnt0) before tid0's release

    // 4) fence-counter: last block of the row proceeds
    if (tid == 0) {
        int old = __hip_atomic_fetch_add(&rowCnt[b], 1, __ATOMIC_ACQ_REL,
                                         __HIP_MEMORY_SCOPE_AGENT);
        sLast = (old == BPR - 1);
    }
    __syncthreads();
    if (!sLast) return;

    // 5) wave 0: word-parallel fire scan
    int wave = tid >> 6, lane = tid & 63;
    if (wave == 0) {
        ulonglong2 pA = pairW[b * 128 + lane];
        ulonglong2 pB = pairW[b * 128 + 64 + lane];
        unsigned long long nA = pA.x, rA = pA.y;
        unsigned long long nB = pB.x, rB = pB.y;
        int lnA = nA ? lane * 64 + 63 - __clzll(nA) : -1;
        int lnB = nB ? (lane + 64) * 64 + 63 - __clzll(nB) : -1;
        int sA = lnA;
        for (int d = 1; d < 64; d <<= 1) { int v = __shfl_up(sA, d); if (lane >= d) sA = max(sA, v); }
        int exA = __shfl_up(sA, 1); if (lane == 0) exA = -1;
        int totA = __shfl(sA, 63);
        int sB = lnB;
        for (int d = 1; d < 64; d <<= 1) { int v = __shfl_up(sB, d); if (lane >= d) sB = max(sB, v); }
        int exB = __shfl_up(sB, 1); if (lane == 0) exB = -1;
        exB = max(exB, totA);

        auto fireWord = [&](unsigned long long nw, unsigned long long rw,
                            int widx, int carry) -> unsigned long long {
            long long wbase = (long long)widx * 64;
            unsigned long long fire = 0, rem = nw;
            long long cur = carry;
            while (true) {
                int nxt = rem ? (__ffsll(rem) - 1) : 64;
                int r = (int)(((cur - wbase) % 32 + 32) % 32);
                unsigned long long pat = (1ULL << r) | (1ULL << (r + 32));
                int s = (int)(cur - wbase + 1); if (s < 0) s = 0;
                fire |= pat & bitsBelow(nxt) & ~bitsBelow(s);
                if (!rem) break;
                fire |= 1ULL << nxt;
                cur = wbase + nxt;
                rem &= rem - 1;
            }
            return fire & rw;
        };
        unsigned long long fA = fireWord(nA, rA, lane, exA);
        unsigned long long fB = fireWord(nB, rB, lane + 64, exB);
        int pcA = __popcll(fA), pcB = __popcll(fB);
        int iA = pcA;
        for (int d = 1; d < 64; d <<= 1) { int v = __shfl_up(iA, d); if (lane >= d) iA += v; }
        int baseA = iA - pcA;
        int totPA = __shfl(iA, 63);
        int iB = pcB;
        for (int d = 1; d < 64; d <<= 1) { int v = __shfl_up(iB, d); if (lane >= d) iB += v; }
        int baseB = totPA + iB - pcB;
        int total = totPA + __shfl(iB, 63);
        unsigned long long f = fA; int idx = baseA;
        while (f) { int tt = __ffsll(f) - 1; sFires[idx++] = lane * 64 + tt; f &= f - 1; }
        f = fB; idx = baseB;
        while (f) { int tt = __ffsll(f) - 1; sFires[idx++] = (lane + 64) * 64 + tt; f &= f - 1; }
        if (lane == 0) sNf = total;
    }
    __syncthreads();

    // 6) sparse rewrite of the row's live phrases
    int nf = sNf;
    int ntask = nf * 8;                       // 8 quads per live phrase
    for (int task = tid; task < ntask; task += TPB) {
        int q = task & 7;
        int p = task >> 3;
        int end   = sFires[p];
        int start = (p > 0) ? (sFires[p - 1] + 1) : 0;
        int len   = end - start + 1;          // 1..32 guaranteed
        int s0 = q * 4;
        int4 mv, tv;
        int* mp = (int*)&mv;
        int* tp = (int*)&tv;
#pragma unroll
        for (int j = 0; j < 4; ++j) {
            int s = s0 + j;
            bool m = s < len;
            mp[j] = m ? 1 : 0;
            tp[j] = m ? (start + s) : 0;
        }
        long long bp = (long long)b * TT + p;
        *(int4*)(out + bp * 32 + q * 4)        = mv;
        *(int4*)(out + MOFF + bp * 32 + q * 4) = tv;
        if (q == 0) out[2 * MOFF + bp] = end;
    }
}

extern "C" void kernel_launch(void* const* d_in, const int* in_sizes, int n_in,
                              void* d_out, int out_size, void* d_ws, size_t ws_size,
                              hipStream_t stream) {
    const int*  ids   = (const int*)d_in[0];
    const void* punct = d_in[1];
    const void* abbr  = d_in[2];
    char* ws = (char*)d_ws;
    int* rowCnt       = (int*)(ws + WS_CNT);
    ulonglong2* pairW = (ulonglong2*)(ws + WS_PAIR);
    int* out = (int*)d_out;

    hipMemsetAsync(rowCnt, 0, BB * sizeof(int), stream);   // deterministic counters
    mono_kernel<<<NB, TPB, 0, stream>>>(ids, punct, abbr, pairW, rowCnt, out);
}

// Round 10
// 55.194 us; speedup vs baseline: 1.4624x; 1.4624x over previous
//
#include <hip/hip_runtime.h>
#include <stdint.h>

// Problem constants (fixed by setup_inputs)
#define BB 64
#define TT 8192
// max_phrase_len = 32, pad_token_id = 0 (hardcoded)

#define TPB    512                     // threads per block
#define SLICES 16                      // blocks per row
#define SL     (TT / SLICES)           // phrases per slice = 512

#define MOFF ((long long)BB * TT * 32) // ints in mask (= ints in tok)

__device__ __forceinline__ unsigned long long bitsBelow(int e) {  // bits 0..e-1, e in [0,64]
    return (e >= 64) ? ~0ULL : ((1ULL << e) - 1ULL);
}

__device__ __forceinline__ bool lut(const void* tbl, int flag, int idx) {
    if (flag == 2) return ((const float*)tbl)[idx]   != 0.0f;
    if (flag == 1) return ((const uint8_t*)tbl)[idx] != 0;
    return ((const int*)tbl)[idx] != 0;
}

// ---------------------------------------------------------------------------
// mono_kernel: ONE dispatch, ZERO cross-block communication (no atomics --
// round 9 showed per-block agent-scope fences collapse store BW 4x on the
// 8-XCD non-coherent L2s).  1024 blocks = 16 slices/row x 512 threads,
// ~37KB LDS -> 4 blocks/CU (2048 thr = full).
//  1) dtype probe of bool tables (0=int32,1=uint8,2=float32) on 4KB.
//  2) whole-row natural/real bits, 16 tokens/thread (row ids are L2/L3-hot
//     across the 16 blocks sharing them; abbr gather predicated ~5%):
//       natural[t] = real && ((punct[id] && !(t>0 && abbr[prev])) || t==last_real)
//       t==last_real local (real prefix): real[t] && (t==T-1 || !real[t+1])
//     16-bit chunks -> LDS, assembled to u64 words (little-endian bit order).
//  3) background stores for this block's OWN slice only: mask=0, tok=0
//     (8+8 int4/thread), end=-1 (1 int/thread).  Fire-and-forget.
//  4) wave 0: verified word-parallel fire scan (runs UNDER the store drain):
//       fire[t] = real[t] && (natural[t] || t === prevNat(t) (mod 32))
//     (init -1 => forced at t%32==31); prevNat carries = exclusive MAX-scan
//     of per-word last-natural positions; per-word fire bits via segment
//     walk; compaction via exclusive ADD-scan.  Fire list -> LDS.
//  5) __syncthreads (compiler-emitted vmcnt(0) drains the bg stores ->
//     write-write order to same addresses is safe) then sparse-rewrite the
//     slice's live phrases (p < nf).  Each address written by exactly ONE
//     block; within-block order by the drain barrier => deterministic.
// ---------------------------------------------------------------------------
__global__ __launch_bounds__(TPB) void mono_kernel(
        const int* __restrict__ ids,
        const void* __restrict__ punct,
        const void* __restrict__ abbr,
        int* __restrict__ out) {
    __shared__ unsigned long long sNat[128], sReal[128];
    __shared__ uint16_t sN16[TPB], sR16[TPB];
    __shared__ int sFires[TT];
    __shared__ int sFlag, sNf;

    int b     = blockIdx.x >> 4;      // row
    int slice = blockIdx.x & 15;      // 512-phrase slice within row
    int tid   = threadIdx.x;
    int wave  = tid >> 6, lane = tid & 63;

    if (tid == 0) sFlag = 0;
    __syncthreads();
    {   // probe first 1024 int32 words (4KB; in-bounds for all 3 layouts)
        const uint32_t* w = (const uint32_t*)punct;
        bool byteGT1 = false, wordGT1 = false;
#pragma unroll
        for (int j = 0; j < 2; ++j) {
            uint32_t x = w[tid * 2 + j];
            byteGT1 |= (x & 0xFEFEFEFEu) != 0u;   // f32: 1.0f has high bytes set
            wordGT1 |= (x > 1u);                  // uint8: packed bools > 1
        }
        int local = (byteGT1 ? 2 : 0) | (wordGT1 ? 1 : 0);
        if (local) atomicOr(&sFlag, local);
    }
    __syncthreads();
    int fl = sFlag;
    int flag = (fl & 2) ? 2 : (fl & 1);

    // 2) whole-row natural/real bits, 16 tokens per thread
    const int* rowIds = ids + b * TT;
    int base = tid * 16;
    int id[17];
    {
        int4 v0 = *(const int4*)(rowIds + base);
        int4 v1 = *(const int4*)(rowIds + base + 4);
        int4 v2 = *(const int4*)(rowIds + base + 8);
        int4 v3 = *(const int4*)(rowIds + base + 12);
        id[0]=v0.x; id[1]=v0.y; id[2]=v0.z;  id[3]=v0.w;
        id[4]=v1.x; id[5]=v1.y; id[6]=v1.z;  id[7]=v1.w;
        id[8]=v2.x; id[9]=v2.y; id[10]=v2.z; id[11]=v2.w;
        id[12]=v3.x; id[13]=v3.y; id[14]=v3.z; id[15]=v3.w;
    }
    id[16] = (tid < TPB - 1) ? rowIds[base + 16] : 0;   // t=TT-1 uses t==TT-1 path
    int prev = (tid > 0) ? rowIds[base - 1] : 0;        // t=0 uses e=pu path
    uint32_t nbits = 0, rbits = 0;
#pragma unroll
    for (int j = 0; j < 16; ++j) {
        int idj = id[j];
        bool real = (idj != 0);
        bool isLR = real && ((base + j == TT - 1) || (id[j + 1] == 0));
        bool e = false;
        if (real && lut(punct, flag, idj)) {
            int pid = j ? id[j - 1] : prev;
            e = (base + j == 0) ? true : !lut(abbr, flag, pid);
        }
        bool nat = real && (e || isLR);
        nbits |= (uint32_t)nat  << j;
        rbits |= (uint32_t)real << j;
    }
    sN16[tid] = (uint16_t)nbits;
    sR16[tid] = (uint16_t)rbits;
    __syncthreads();
    if (tid < 128) {
        sNat[tid]  = *(const unsigned long long*)&sN16[tid * 4];
        sReal[tid] = *(const unsigned long long*)&sR16[tid * 4];
    }
    __syncthreads();

    // 3) background stores for this block's slice (fire-and-forget)
    {
        long long mbase = ((long long)b * TT + slice * SL) * 32;   // int idx
        int4 z = make_int4(0, 0, 0, 0);
#pragma unroll
        for (int k = 0; k < 8; ++k) {
            *(int4*)(out + mbase + (k * TPB + tid) * 4) = z;
        }
#pragma unroll
        for (int k = 0; k < 8; ++k) {
            *(int4*)(out + MOFF + mbase + (k * TPB + tid) * 4) = z;
        }
        out[2 * MOFF + b * TT + slice * SL + tid] = -1;
    }

    // 4) wave 0: word-parallel fire scan (hidden under the store drain)
    if (wave == 0) {
        unsigned long long nA = sNat[lane],  nB = sNat[lane + 64];
        unsigned long long rA = sReal[lane], rB = sReal[lane + 64];
        int lnA = nA ? lane * 64 + 63 - __clzll(nA) : -1;
        int lnB = nB ? (lane + 64) * 64 + 63 - __clzll(nB) : -1;
        int sA = lnA;
        for (int d = 1; d < 64; d <<= 1) { int v = __shfl_up(sA, d); if (lane >= d) sA = max(sA, v); }
        int exA = __shfl_up(sA, 1); if (lane == 0) exA = -1;
        int totA = __shfl(sA, 63);
        int sB = lnB;
        for (int d = 1; d < 64; d <<= 1) { int v = __shfl_up(sB, d); if (lane >= d) sB = max(sB, v); }
        int exB = __shfl_up(sB, 1); if (lane == 0) exB = -1;
        exB = max(exB, totA);

        auto fireWord = [&](unsigned long long nw, unsigned long long rw,
                            int widx, int carry) -> unsigned long long {
            long long wbase = (long long)widx * 64;
            unsigned long long fire = 0, rem = nw;
            long long cur = carry;
            while (true) {
                int nxt = rem ? (__ffsll(rem) - 1) : 64;
                int r = (int)(((cur - wbase) % 32 + 32) % 32);
                unsigned long long pat = (1ULL << r) | (1ULL << (r + 32));
                int s = (int)(cur - wbase + 1); if (s < 0) s = 0;
                fire |= pat & bitsBelow(nxt) & ~bitsBelow(s);
                if (!rem) break;
                fire |= 1ULL << nxt;
                cur = wbase + nxt;
                rem &= rem - 1;
            }
            return fire & rw;
        };
        unsigned long long fA = fireWord(nA, rA, lane, exA);
        unsigned long long fB = fireWord(nB, rB, lane + 64, exB);
        int pcA = __popcll(fA), pcB = __popcll(fB);
        int iA = pcA;
        for (int d = 1; d < 64; d <<= 1) { int v = __shfl_up(iA, d); if (lane >= d) iA += v; }
        int baseA = iA - pcA;
        int totPA = __shfl(iA, 63);
        int iB = pcB;
        for (int d = 1; d < 64; d <<= 1) { int v = __shfl_up(iB, d); if (lane >= d) iB += v; }
        int baseB = totPA + iB - pcB;
        int total = totPA + __shfl(iB, 63);
        unsigned long long f = fA; int idx = baseA;
        while (f) { int tt = __ffsll(f) - 1; sFires[idx++] = lane * 64 + tt; f &= f - 1; }
        f = fB; idx = baseB;
        while (f) { int tt = __ffsll(f) - 1; sFires[idx++] = (lane + 64) * 64 + tt; f &= f - 1; }
        if (lane == 0) sNf = total;
    }
    __syncthreads();   // vmcnt(0) drain: bg stores complete before rewrites

    // 5) sparse rewrite of this slice's live phrases
    int nf  = sNf;
    int p0  = slice * SL;
    int cnt = nf - p0;
    if (cnt > SL) cnt = SL;
    if (cnt > 0) {
        int ntask = cnt * 8;
        for (int task = tid; task < ntask; task += TPB) {
            int q  = task & 7;
            int p  = p0 + (task >> 3);
            int end   = sFires[p];
            int start = (p > 0) ? (sFires[p - 1] + 1) : 0;
            int len   = end - start + 1;      // 1..32 guaranteed
            int s0 = q * 4;
            int4 mv, tv;
            int* mp = (int*)&mv;
            int* tp = (int*)&tv;
#pragma unroll
            for (int j = 0; j < 4; ++j) {
                int s = s0 + j;
                bool m = s < len;
                mp[j] = m ? 1 : 0;
                tp[j] = m ? (start + s) : 0;
            }
            long long bp = (long long)b * TT + p;
            *(int4*)(out + bp * 32 + q * 4)        = mv;
            *(int4*)(out + MOFF + bp * 32 + q * 4) = tv;
            if (q == 0) out[2 * MOFF + bp] = end;
        }
    }
}

extern "C" void kernel_launch(void* const* d_in, const int* in_sizes, int n_in,
                              void* d_out, int out_size, void* d_ws, size_t ws_size,
                              hipStream_t stream) {
    const int*  ids   = (const int*)d_in[0];
    const void* punct = d_in[1];
    const void* abbr  = d_in[2];
    int* out = (int*)d_out;

    mono_kernel<<<BB * SLICES, TPB, 0, stream>>>(ids, punct, abbr, out);
}